// Round 5
// baseline (220.874 us; speedup 1.0000x reference)
//
#include <hip/hip_runtime.h>
#include <stdint.h>
#include <stddef.h>

// Problem constants
#define B_ 4
#define L_ 8192
#define D_ 512
#define M_ (B_*L_)      // 32768 rows
#define K_ 512
#define CHUNK 64
#define NC (L_/CHUNK)   // 128 chunks per sequence

typedef _Float16 f16;
typedef f16 f16x2 __attribute__((ext_vector_type(2)));
typedef f16 f16x4 __attribute__((ext_vector_type(4)));
typedef f16 f16x8 __attribute__((ext_vector_type(8)));
typedef __fp16 h16x2 __attribute__((ext_vector_type(2)));   // cvt_pkrtz result type
typedef float f32x4 __attribute__((ext_vector_type(4)));

__device__ __forceinline__ uint32_t pack2(float a, float b) {
  h16x2 p = __builtin_amdgcn_cvt_pkrtz(a, b);
  return __builtin_bit_cast(uint32_t, p);
}

// ---------------- async global->LDS (16B/lane) ----------------
__device__ __forceinline__ void async16(const void* g, void* l) {
  __builtin_amdgcn_global_load_lds(
      (const __attribute__((address_space(1))) uint32_t*)g,
      (__attribute__((address_space(3))) uint32_t*)l,
      16, 0, 0);
}

// ---------------- fp32 -> f16 conversion of x ----------------
__global__ __launch_bounds__(256) void cvt_x(const float* __restrict__ x,
                                             f16* __restrict__ xh) {
  int idx = (blockIdx.x * 256 + threadIdx.x) * 4;
  float4 v = *(const float4*)(x + idx);
  f16x4 o = {(f16)v.x, (f16)v.y, (f16)v.z, (f16)v.w};
  *(f16x4*)(xh + idx) = o;
}

// ---------------- pack Wg ++ Wc into f16 [1024][512] ----------------
__global__ __launch_bounds__(256) void pack_w(const float* __restrict__ Wg,
                                              const float* __restrict__ Wc,
                                              f16* __restrict__ wp) {
  int idx = (blockIdx.x * 256 + threadIdx.x) * 4;  // 0..524287
  const float* src = (idx < 262144) ? (Wg + idx) : (Wc + (idx - 262144));
  float4 v = *(const float4*)src;
  f16x4 o = {(f16)v.x, (f16)v.y, (f16)v.z, (f16)v.w};
  *(f16x4*)(wp + idx) = o;
}

// ---------------- fused dual-B GEMM, packed f16x2 pre-activation out -----
// yg = Xh·Wg^T + bg ; yc = Xh·Wc^T + bc
// AC[m*512 + col] = pack_f16x2(yg, yc)   (activations applied in scan_local)
__global__ __launch_bounds__(256, 2) void gemm_act(
    const f16* __restrict__ Xh, const f16* __restrict__ Wp,
    const float* __restrict__ bg, const float* __restrict__ bc,
    uint32_t* __restrict__ AC) {
  __shared__ __align__(16) f16 sA[128 * 32];
  __shared__ __align__(16) f16 sBg[128 * 32];
  __shared__ __align__(16) f16 sBc[128 * 32];

  const int tid = threadIdx.x;
  // XCD swizzle: same bm-tile's 4 col-blocks run consecutively on one XCD
  const int id = blockIdx.x;           // 0..1023
  const int xcd = id & 7;
  const int slot = id >> 3;            // 0..127
  const int g_ = xcd * 128 + slot;
  const int bm = g_ >> 2;              // 0..255
  const int bn = g_ & 3;               // 0..3 (128-col tiles)

  const int lane = tid & 63;
  const int w = tid >> 6;
  const int wm = w >> 1, wn = w & 1;   // 2x2 wave grid over 128x128
  const int l15 = lane & 15, quad = lane >> 4;

  // staging: tid -> (row = tid>>2, 16B piece = tid&3)
  const int srow = tid >> 2;
  const int spc8 = (tid & 3) * 8;
  const f16* gA  = Xh + (size_t)(bm * 128 + srow) * K_ + spc8;
  const f16* gBg = Wp + (size_t)(bn * 128 + srow) * K_ + spc8;
  const f16* gBc = Wp + (size_t)(512 + bn * 128 + srow) * K_ + spc8;
  f16* lA  = sA  + tid * 8;
  f16* lBg = sBg + tid * 8;
  f16* lBc = sBc + tid * 8;

  f32x4 accG[4][4] = {};
  f32x4 accC[4][4] = {};

  for (int k0 = 0; k0 < K_; k0 += 32) {
    async16(gA + k0,  lA);
    async16(gA + (size_t)64 * K_ + k0,  lA  + 64 * 32);
    async16(gBg + k0, lBg);
    async16(gBg + (size_t)64 * K_ + k0, lBg + 64 * 32);
    async16(gBc + k0, lBc);
    async16(gBc + (size_t)64 * K_ + k0, lBc + 64 * 32);
    __syncthreads();  // drains vmcnt then barrier

    f16x8 af[4], bgf[4], bcf[4];
#pragma unroll
    for (int i = 0; i < 4; i++)
      af[i]  = *(const f16x8*)(sA  + (wm * 64 + i * 16 + l15) * 32 + quad * 8);
#pragma unroll
    for (int j = 0; j < 4; j++) {
      bgf[j] = *(const f16x8*)(sBg + (wn * 64 + j * 16 + l15) * 32 + quad * 8);
      bcf[j] = *(const f16x8*)(sBc + (wn * 64 + j * 16 + l15) * 32 + quad * 8);
    }
#pragma unroll
    for (int i = 0; i < 4; i++)
#pragma unroll
      for (int j = 0; j < 4; j++) {
        accG[i][j] = __builtin_amdgcn_mfma_f32_16x16x32_f16(af[i], bgf[j], accG[i][j], 0, 0, 0);
        accC[i][j] = __builtin_amdgcn_mfma_f32_16x16x32_f16(af[i], bcf[j], accC[i][j], 0, 0, 0);
      }
    __syncthreads();
  }

  // epilogue: add bias, pack (yg, yc) as f16x2 -> one 4B store per cell
#pragma unroll
  for (int j = 0; j < 4; j++) {
    const int col = bn * 128 + wn * 64 + j * 16 + l15;   // 0..511
    const float bgv = bg[col];
    const float bcv = bc[col];
#pragma unroll
    for (int i = 0; i < 4; i++) {
      const int mrow = bm * 128 + wm * 64 + i * 16 + quad * 4;
#pragma unroll
      for (int r = 0; r < 4; r++) {
        float yg = accG[i][j][r] + bgv;
        float yc = accC[i][j][r] + bcv;
        AC[(size_t)(mrow + r) * 512 + col] = pack2(yg, yc);
      }
    }
  }
}

// ---------------- scan pass 1: activations + per-chunk composite ---------
// Reads packed preacts (yg,yc); computes a = 1-sigmoid(yg),
// b = sigmoid(yg)*tanh(yc); overwrites AC in place with packed (a,b)
// (same index, same thread -> race-free); writes chunk composite (P,Q).
__global__ __launch_bounds__(512) void scan_local(
    uint32_t* __restrict__ AC,
    float* __restrict__ cA, float* __restrict__ cB) {
  const int blk = blockIdx.x;          // 0..511 = b*NC + ch
  const int d = threadIdx.x;
  const size_t base = (size_t)blk * CHUNK * 512 + d;
  float P = 1.0f, Q = 0.0f;
#pragma unroll 4
  for (int t = 0; t < CHUNK; t++) {
    const size_t i = base + (size_t)t * 512;
    f16x2 v = __builtin_bit_cast(f16x2, AC[i]);
    float yg = (float)v[0];
    float yc = (float)v[1];
    float a = 1.0f / (1.0f + __expf(yg));          // 1 - sigmoid(yg)
    float e = __expf(fmaxf(-2.0f * yc, -30.0f));   // tanh via exp(-2x)
    float c = (1.0f - e) / (1.0f + e);             // tanh(yc)
    float b = (1.0f - a) * c;
    AC[i] = pack2(a, b);
    Q = fmaf(a, Q, b);
    P *= a;
  }
  cA[blk * 512 + d] = P;
  cB[blk * 512 + d] = Q;
}

// ---------------- scan pass 2: prefix over chunks ----------------
__global__ __launch_bounds__(64) void scan_chunks(
    const float* __restrict__ cA, const float* __restrict__ cB,
    float* __restrict__ Hp) {
  const int b = blockIdx.x >> 3;
  const int d = ((blockIdx.x & 7) << 6) + threadIdx.x;
  float h = 0.0f;
#pragma unroll 8
  for (int ch = 0; ch < NC; ch++) {
    const int idx = (b * NC + ch) * 512 + d;
    Hp[idx] = h;                       // h entering chunk ch
    h = fmaf(cA[idx], h, cB[idx]);
  }
}

// ---------------- scan pass 3: apply prefix, write h ----------------
__global__ __launch_bounds__(512) void scan_apply(
    const uint32_t* __restrict__ AC, const float* __restrict__ Hp,
    float* __restrict__ out) {
  const int blk = blockIdx.x;
  const int d = threadIdx.x;
  const size_t base = (size_t)blk * CHUNK * 512 + d;
  float h = Hp[blk * 512 + d];
#pragma unroll 4
  for (int t = 0; t < CHUNK; t++) {
    const size_t i = base + (size_t)t * 512;
    f16x2 v = __builtin_bit_cast(f16x2, AC[i]);
    h = fmaf((float)v[0], h, (float)v[1]);
    out[i] = h;
  }
}

// ---------------- launch ----------------
extern "C" void kernel_launch(void* const* d_in, const int* in_sizes, int n_in,
                              void* d_out, int out_size, void* d_ws, size_t ws_size,
                              hipStream_t stream) {
  const float* x  = (const float*)d_in[0];
  const float* Wg = (const float*)d_in[1];
  const float* bg = (const float*)d_in[2];
  const float* Wc = (const float*)d_in[3];
  const float* bc = (const float*)d_in[4];
  float* out = (float*)d_out;

  char* ws = (char*)d_ws;
  // workspace layout (bytes):
  //   [0, 32MB)      xh   f16 x
  //   [32MB, 33MB)   wp   f16 packed weights [1024][512]
  //   [33MB, 97MB)   AC   u32 packed f16x2: preacts (yg,yc), then (a,b)
  //   [97MB..]       cA, cB, Hp fp32 (1MB each)
  f16*      xh = (f16*)(ws);
  f16*      wp = (f16*)(ws + 33554432);
  uint32_t* AC = (uint32_t*)(ws + 34603008);
  float*    cA = (float*)(ws + 101711872);
  float*    cB = (float*)(ws + 102760448);
  float*    Hp = (float*)(ws + 103809024);

  cvt_x<<<M_ * D_ / (256 * 4), 256, 0, stream>>>(x, xh);
  pack_w<<<2 * D_ * D_ / (256 * 4), 256, 0, stream>>>(Wg, Wc, wp);
  gemm_act<<<(M_ / 128) * 4, 256, 0, stream>>>(xh, wp, bg, bc, AC);
  scan_local<<<B_ * NC, 512, 0, stream>>>(AC, cA, cB);
  scan_chunks<<<32, 64, 0, stream>>>(cA, cB, Hp);
  scan_apply<<<B_ * NC, 512, 0, stream>>>(AC, Hp, out);
}